// Round 1
// baseline (289.602 us; speedup 1.0000x reference)
//
#include <hip/hip_runtime.h>

// QuaternionLinear as one 4096^3 bf16 GEMM (B^T layout), m97-ladder structure.
// out[b][o*4+d] = sum_{i,c} x[b][i*4+c] * Wbig[o*4+d][i*4+c] + bias[o*4+d]
// Wbig rows (c order) per quaternion w=(r,i,j,k):
//   d=0: [+r, -i, -j, -k]
//   d=1: [+i, +r, +k, -j]
//   d=2: [+j, -k, +r, +i]
//   d=3: [+k, +j, -i, +r]

typedef __bf16 bf16x8 __attribute__((ext_vector_type(8)));
typedef __bf16 bf16x4 __attribute__((ext_vector_type(4)));
typedef float floatx4 __attribute__((ext_vector_type(4)));

constexpr int M = 4096;   // batch
constexpr int N = 4096;   // out_f * 4
constexpr int K = 4096;   // in_f * 4
constexpr int BM = 128, BN = 128, BK = 32;

// ---------- conversion: x fp32 -> bf16 A[M][K] ----------
__global__ void cvt_x_kernel(const float* __restrict__ x, __bf16* __restrict__ o) {
    const size_t i = (size_t)blockIdx.x * blockDim.x + threadIdx.x;  // 8 elems/thread
    const float4* xp = (const float4*)x;
    float4 a = xp[2 * i];
    float4 b = xp[2 * i + 1];
    bf16x8 v;
    v[0] = (__bf16)a.x; v[1] = (__bf16)a.y; v[2] = (__bf16)a.z; v[3] = (__bf16)a.w;
    v[4] = (__bf16)b.x; v[5] = (__bf16)b.y; v[6] = (__bf16)b.z; v[7] = (__bf16)b.w;
    *(bf16x8*)(o + 8 * i) = v;
}

// ---------- expansion: weight fp32 (o,i,4) -> bf16 Wbig[N][K] with signs ----------
__global__ void expand_w_kernel(const float* __restrict__ w, __bf16* __restrict__ wb) {
    const int idx = blockIdx.x * blockDim.x + threadIdx.x;  // one per (o,i)
    const int o = idx >> 10;
    const int i = idx & 1023;
    float4 q = ((const float4*)w)[idx];   // r,i,j,k
    bf16x4 r0, r1, r2, r3;
    r0[0] = (__bf16)q.x;  r0[1] = (__bf16)(-q.y); r0[2] = (__bf16)(-q.z); r0[3] = (__bf16)(-q.w);
    r1[0] = (__bf16)q.y;  r1[1] = (__bf16)q.x;   r1[2] = (__bf16)q.w;    r1[3] = (__bf16)(-q.z);
    r2[0] = (__bf16)q.z;  r2[1] = (__bf16)(-q.w); r2[2] = (__bf16)q.x;   r2[3] = (__bf16)q.y;
    r3[0] = (__bf16)q.w;  r3[1] = (__bf16)q.z;   r3[2] = (__bf16)(-q.y); r3[3] = (__bf16)q.x;
    __bf16* base = wb + (size_t)(o * 4) * K + i * 4;
    *(bf16x4*)(base)                 = r0;
    *(bf16x4*)(base + (size_t)K)     = r1;
    *(bf16x4*)(base + (size_t)2 * K) = r2;
    *(bf16x4*)(base + (size_t)3 * K) = r3;
}

// ---------- async global->LDS, 16B per lane ----------
__device__ __forceinline__ void gload_lds16(const __bf16* g, __bf16* l) {
    __builtin_amdgcn_global_load_lds(
        (const __attribute__((address_space(1))) void*)g,
        (__attribute__((address_space(3))) void*)l, 16, 0, 0);
}

// ---------- GEMM: C[M][N] = A[M][K] * B[N][K]^T + bias[N] ----------
__global__ void qgemm_kernel(const __bf16* __restrict__ A,
                             const __bf16* __restrict__ B,
                             const float* __restrict__ bias,
                             float* __restrict__ C) {
    __shared__ __bf16 As[BM][BK];
    __shared__ __bf16 Bs[BN][BK];

    const int tid  = threadIdx.x;
    const int wave = tid >> 6;
    const int lane = tid & 63;
    const int bm = blockIdx.y * BM;
    const int bn = blockIdx.x * BN;
    const int wm = (wave & 1) * 64;   // wave's C-subtile origin
    const int wn = (wave >> 1) * 64;

    // staging: each wave covers 16 rows x 32 cols per issue; lane -> (row, col8)
    const int ldrow = lane >> 2;
    const int ldcol = (lane & 3) * 8;

    const __bf16* ag0 = A + (size_t)(bm + wave * 16 + ldrow) * K + ldcol;
    const __bf16* ag1 = ag0 + (size_t)64 * K;
    const __bf16* bg0 = B + (size_t)(bn + wave * 16 + ldrow) * K + ldcol;
    const __bf16* bg1 = bg0 + (size_t)64 * K;

    __bf16* as0 = &As[wave * 16][0];        // wave-uniform base; HW adds lane*16B
    __bf16* as1 = &As[64 + wave * 16][0];
    __bf16* bs0 = &Bs[wave * 16][0];
    __bf16* bs1 = &Bs[64 + wave * 16][0];

    floatx4 acc[4][4] = {};

    const int fl = lane & 15;          // m (A) / n (B) index within 16
    const int fk = (lane >> 4) * 8;    // k offset within BK

    for (int k0 = 0; k0 < K; k0 += BK) {
        gload_lds16(ag0 + k0, as0);
        gload_lds16(ag1 + k0, as1);
        gload_lds16(bg0 + k0, bs0);
        gload_lds16(bg1 + k0, bs1);
        __syncthreads();

        bf16x8 af[4], bfr[4];
#pragma unroll
        for (int t = 0; t < 4; ++t)
            af[t] = *(const bf16x8*)&As[wm + t * 16 + fl][fk];
#pragma unroll
        for (int t = 0; t < 4; ++t)
            bfr[t] = *(const bf16x8*)&Bs[wn + t * 16 + fl][fk];

#pragma unroll
        for (int mt = 0; mt < 4; ++mt)
#pragma unroll
            for (int nt = 0; nt < 4; ++nt)
                acc[mt][nt] = __builtin_amdgcn_mfma_f32_16x16x32_bf16(
                    af[mt], bfr[nt], acc[mt][nt], 0, 0, 0);
        __syncthreads();
    }

    // epilogue: C/D layout col = lane&15, row = (lane>>4)*4 + reg
#pragma unroll
    for (int mt = 0; mt < 4; ++mt) {
        const int row = bm + wm + mt * 16 + (lane >> 4) * 4;
#pragma unroll
        for (int nt = 0; nt < 4; ++nt) {
            const int col = bn + wn + nt * 16 + fl;
            const float bv = bias[col];
            float* cp = C + (size_t)row * N + col;
#pragma unroll
            for (int r = 0; r < 4; ++r)
                cp[(size_t)r * N] = acc[mt][nt][r] + bv;
        }
    }
}

extern "C" void kernel_launch(void* const* d_in, const int* in_sizes, int n_in,
                              void* d_out, int out_size, void* d_ws, size_t ws_size,
                              hipStream_t stream) {
    const float* x    = (const float*)d_in[0];   // (4096,1024,4) fp32
    const float* w    = (const float*)d_in[1];   // (1024,1024,4) fp32
    const float* bias = (const float*)d_in[2];   // (1024,4) fp32
    float* out = (float*)d_out;                  // (4096,1024,4) fp32

    __bf16* Abf  = (__bf16*)d_ws;                                   // 32 MB
    __bf16* Wbig = (__bf16*)((char*)d_ws + (size_t)M * K * 2);      // 32 MB

    cvt_x_kernel<<<(M * K / 8) / 256, 256, 0, stream>>>(x, Abf);
    expand_w_kernel<<<(1024 * 1024) / 256, 256, 0, stream>>>(w, Wbig);

    dim3 grid(N / BN, M / BM);  // 32 x 32
    qgemm_kernel<<<grid, 256, 0, stream>>>(Abf, Wbig, bias, out);
}